// Round 1
// baseline (2892.907 us; speedup 1.0000x reference)
//
#include <hip/hip_runtime.h>
#include <hip/hip_bf16.h>
#include <math.h>

// ---- problem constants ----
#define BATCH   2
#define TSEQ    512
#define NDIM    256
#define STRIDE_ 4
#define KLEN    14
#define DM      3584        // NDIM*KLEN
#define DI      7168        // 2*DM
#define DTR     224
#define DSTATE  16
#define NCLS    41
#define LOUT    125
#define LPAD    128         // padded rows per batch
#define MROWS   256         // BATCH*LPAD

// ---------------------------------------------------------------------------
// day projection + softsign: t[b,i,k] = softsign(sum_d nI[b,i,d]*dw[di,d,k]+db)
__global__ void day_proj(const float* __restrict__ nI, const float* __restrict__ dw,
                         const float* __restrict__ db, const int* __restrict__ dayIdx,
                         float* __restrict__ t_full) {
    int bi = blockIdx.x;               // b*512 + i
    int b = bi >> 9;
    int di = dayIdx[b];
    int tid = threadIdx.x;             // k
    __shared__ float a_sh[256];
    a_sh[tid] = nI[(size_t)bi * 256 + tid];
    __syncthreads();
    const float* w = dw + (size_t)di * 65536;
    float acc = db[(size_t)di * 256 + tid];
    #pragma unroll 4
    for (int d = 0; d < 256; ++d) acc = fmaf(a_sh[d], w[d * 256 + tid], acc);
    t_full[(size_t)bi * 256 + tid] = acc / (1.f + fabsf(acc));
}

// window gather: res[b*128+l][d*14+j] = t[b, l*4+j, d]
__global__ void window_k(const float* __restrict__ t_full, float* __restrict__ res) {
    int bl = blockIdx.x;               // 0..249
    int b = bl / 125, l = bl % 125;
    size_t m = (size_t)b * LPAD + l;
    for (int c = threadIdx.x; c < DM; c += 256) {
        int d = c / KLEN, j = c - d * KLEN;
        res[m * DM + c] = t_full[((size_t)b * TSEQ + l * STRIDE_ + j) * 256 + d];
    }
}

// layernorm over DM, one block per row
__global__ void ln_kernel(const float* __restrict__ res, const float* __restrict__ w,
                          const float* __restrict__ b, float* __restrict__ hn) {
    int m = blockIdx.x, tid = threadIdx.x;
    const float* row = res + (size_t)m * DM;
    float s = 0.f, ss = 0.f;
    for (int c = tid; c < DM; c += 256) { float v = row[c]; s += v; ss += v * v; }
    #pragma unroll
    for (int o = 32; o; o >>= 1) { s += __shfl_xor(s, o); ss += __shfl_xor(ss, o); }
    __shared__ float sm[8];
    int wid = tid >> 6;
    if ((tid & 63) == 0) { sm[wid] = s; sm[4 + wid] = ss; }
    __syncthreads();
    s = sm[0] + sm[1] + sm[2] + sm[3];
    ss = sm[4] + sm[5] + sm[6] + sm[7];
    float mu = s * (1.f / DM);
    float var = ss * (1.f / DM) - mu * mu;
    float rs = rsqrtf(var + 1e-5f);
    for (int c = tid; c < DM; c += 256)
        hn[(size_t)m * DM + c] = (row[c] - mu) * rs * w[c] + b[c];
}

// ---------------------------------------------------------------------------
// generic fp32 GEMM: C[MROWS x N] (+)= A[MROWS x K] * W[N x K]^T
// block tile 128x128, thread tile 8x8. EPI: 0=store, 1=softplus(bias+acc),
// 2=atomicAdd into C, 3=store to partial slab blockIdx.z
template <int EPI>
__global__ __launch_bounds__(256, 2)
void gemm128(const float* __restrict__ A, int lda,
             const float* __restrict__ W, int ldw,
             float* __restrict__ C, int ldc,
             int kChunk, const float* __restrict__ bias, long partStride) {
    __shared__ __align__(16) float a_s[16][132];
    __shared__ __align__(16) float w_s[16][132];
    const int tid = threadIdx.x;
    const int n0 = blockIdx.x * 128;
    const int m0 = blockIdx.y * 128;
    const int kBeg = blockIdx.z * kChunk;
    const int mg = tid >> 4;    // 0..15
    const int ng = tid & 15;    // 0..15
    const int r0 = tid >> 2;    // 0..63
    const int q0 = tid & 3;

    float acc[8][8];
    #pragma unroll
    for (int i = 0; i < 8; ++i)
        #pragma unroll
        for (int j = 0; j < 8; ++j) acc[i][j] = 0.f;

    for (int kc = kBeg; kc < kBeg + kChunk; kc += 16) {
        #pragma unroll
        for (int it = 0; it < 2; ++it) {
            int r = r0 + it * 64;
            float4 av = *(const float4*)(A + (size_t)(m0 + r) * lda + kc + q0 * 4);
            a_s[q0 * 4 + 0][r] = av.x; a_s[q0 * 4 + 1][r] = av.y;
            a_s[q0 * 4 + 2][r] = av.z; a_s[q0 * 4 + 3][r] = av.w;
            float4 wv = *(const float4*)(W + (size_t)(n0 + r) * ldw + kc + q0 * 4);
            w_s[q0 * 4 + 0][r] = wv.x; w_s[q0 * 4 + 1][r] = wv.y;
            w_s[q0 * 4 + 2][r] = wv.z; w_s[q0 * 4 + 3][r] = wv.w;
        }
        __syncthreads();
        #pragma unroll
        for (int k = 0; k < 16; ++k) {
            float a[8], w[8];
            *(float4*)&a[0] = *(const float4*)&a_s[k][mg * 8];
            *(float4*)&a[4] = *(const float4*)&a_s[k][mg * 8 + 4];
            *(float4*)&w[0] = *(const float4*)&w_s[k][ng * 8];
            *(float4*)&w[4] = *(const float4*)&w_s[k][ng * 8 + 4];
            #pragma unroll
            for (int i = 0; i < 8; ++i)
                #pragma unroll
                for (int j = 0; j < 8; ++j) acc[i][j] = fmaf(a[i], w[j], acc[i][j]);
        }
        __syncthreads();
    }

    float* Cb = C + ((EPI == 3) ? (size_t)blockIdx.z * (size_t)partStride : 0);
    #pragma unroll
    for (int i = 0; i < 8; ++i) {
        int m = m0 + mg * 8 + i;
        #pragma unroll
        for (int j = 0; j < 8; ++j) {
            int n = n0 + ng * 8 + j;
            float v = acc[i][j];
            if (EPI == 0 || EPI == 3) {
                Cb[(size_t)m * ldc + n] = v;
            } else if (EPI == 1) {
                v += bias[n];
                Cb[(size_t)m * ldc + n] = (v > 20.f) ? v : log1pf(expf(v));
            } else if (EPI == 2) {
                atomicAdd(&Cb[(size_t)m * ldc + n], v);
            }
        }
    }
}

// reduce split-K partials for x_proj: xdbl = sum_z part[z]
__global__ void reduce_part(const float* __restrict__ part, float* __restrict__ outb) {
    int idx = blockIdx.x * 256 + threadIdx.x;     // < 65536
    float s = 0.f;
    #pragma unroll
    for (int z = 0; z < 28; ++z) s += part[(size_t)z * 65536 + idx];
    outb[idx] = s;
}

// causal depthwise conv (DCONV=4) + silu; x half of xz -> xq
__global__ void conv_silu(const float* __restrict__ xz, const float* __restrict__ cw,
                          const float* __restrict__ cb, float* __restrict__ xq) {
    int bl = blockIdx.x;
    int b = bl / 125, l = bl % 125;
    size_t m = (size_t)b * LPAD + l;
    for (int c = threadIdx.x; c < DI; c += 256) {
        float acc = cb[c];
        #pragma unroll
        for (int j = 0; j < 4; ++j) {
            int lj = l - 3 + j;
            if (lj >= 0)
                acc = fmaf(xz[((size_t)b * LPAD + lj) * (2 * DI) + c], cw[c * 4 + j], acc);
        }
        xq[m * DI + c] = acc / (1.f + expf(-acc));   // silu
    }
}

// selective scan: one thread per (b, channel c); 16-state recurrence in regs
__global__ void scan_kernel(const float* __restrict__ delta, const float* __restrict__ xq,
                            const float* __restrict__ xdbl, const float* __restrict__ xz,
                            const float* __restrict__ Alog, const float* __restrict__ Dp,
                            float* __restrict__ y) {
    int c = blockIdx.x * 256 + threadIdx.x;   // 0..7167
    int b = blockIdx.y;
    float As[DSTATE], st[DSTATE];
    #pragma unroll
    for (int s = 0; s < DSTATE; ++s) {
        As[s] = -expf(Alog[(size_t)c * DSTATE + s]);
        st[s] = 0.f;
    }
    float dp = Dp[c];
    for (int l = 0; l < LOUT; ++l) {
        size_t m = (size_t)b * LPAD + l;
        float d  = delta[m * DI + c];
        float xv = xq[m * DI + c];
        float du = d * xv;
        const float* bc = xdbl + m * 256 + DTR;           // 16
        const float* cc = xdbl + m * 256 + DTR + DSTATE;  // 16
        float yv = 0.f;
        #pragma unroll
        for (int s = 0; s < DSTATE; ++s) {
            st[s] = fmaf(expf(d * As[s]), st[s], du * bc[s]);
            yv = fmaf(st[s], cc[s], yv);
        }
        float zv = xz[m * (2 * DI) + DI + c];
        y[m * DI + c] = (yv + xv * dp) * (zv / (1.f + expf(-zv)));
    }
}

// final layernorm + fc head, one block per (b,l)
__global__ void ln_fc(const float* __restrict__ res, const float* __restrict__ wf,
                      const float* __restrict__ bf, const float* __restrict__ fcw,
                      const float* __restrict__ fcb, float* __restrict__ out) {
    __shared__ __align__(16) float hs[DM];
    __shared__ float sm[8];
    int bl = blockIdx.x;
    int b = bl / 125, l = bl % 125;
    size_t m = (size_t)b * LPAD + l;
    int tid = threadIdx.x;
    const float* row = res + m * DM;
    float s = 0.f, ss = 0.f;
    for (int c = tid; c < DM; c += 256) { float v = row[c]; s += v; ss += v * v; }
    #pragma unroll
    for (int o = 32; o; o >>= 1) { s += __shfl_xor(s, o); ss += __shfl_xor(ss, o); }
    int wid = tid >> 6;
    if ((tid & 63) == 0) { sm[wid] = s; sm[4 + wid] = ss; }
    __syncthreads();
    s = sm[0] + sm[1] + sm[2] + sm[3];
    ss = sm[4] + sm[5] + sm[6] + sm[7];
    float mu = s * (1.f / DM);
    float var = ss * (1.f / DM) - mu * mu;
    float rs = rsqrtf(var + 1e-5f);
    for (int c = tid; c < DM; c += 256) hs[c] = (row[c] - mu) * rs * wf[c] + bf[c];
    __syncthreads();
    int lane = tid & 63;
    for (int n = wid; n < NCLS; n += 4) {
        float acc = 0.f;
        for (int k = lane; k < DM; k += 64) acc = fmaf(hs[k], fcw[(size_t)n * DM + k], acc);
        #pragma unroll
        for (int o = 32; o; o >>= 1) acc += __shfl_xor(acc, o);
        if (lane == 0) out[((size_t)b * LOUT + l) * NCLS + n] = acc + fcb[n];
    }
}

// ---------------------------------------------------------------------------
extern "C" void kernel_launch(void* const* d_in, const int* in_sizes, int n_in,
                              void* d_out, int out_size, void* d_ws, size_t ws_size,
                              hipStream_t stream) {
    (void)in_sizes; (void)n_in; (void)out_size; (void)ws_size;
    const float* nI   = (const float*)d_in[0];
    const float* dw   = (const float*)d_in[1];
    const float* db   = (const float*)d_in[2];
    const float* nw   = (const float*)d_in[3];
    const float* nb   = (const float*)d_in[4];
    const float* ipw  = (const float*)d_in[5];
    const float* cw   = (const float*)d_in[6];
    const float* cb   = (const float*)d_in[7];
    const float* xpw  = (const float*)d_in[8];
    const float* dtw  = (const float*)d_in[9];
    const float* dtb  = (const float*)d_in[10];
    const float* Alog = (const float*)d_in[11];
    const float* Dp   = (const float*)d_in[12];
    const float* opw  = (const float*)d_in[13];
    const float* nfw  = (const float*)d_in[14];
    const float* nfb  = (const float*)d_in[15];
    const float* fcw  = (const float*)d_in[16];
    const float* fcb  = (const float*)d_in[17];
    const int*   dayI = (const int*)d_in[18];
    float* out = (float*)d_out;

    float* ws = (float*)d_ws;
    float* t_full = ws; ws += 262144;              // B*T*ND
    float* res    = ws; ws += (size_t)MROWS * DM;  // 917504
    float* hn     = ws; ws += (size_t)MROWS * DM;
    float* xz     = ws; ws += (size_t)MROWS * 2 * DI;  // 3670016
    float* xq     = ws; ws += (size_t)MROWS * DI;
    float* xdbl   = ws; ws += (size_t)MROWS * 256;
    float* xpart  = ws; ws += (size_t)28 * MROWS * 256;
    float* delta  = ws; ws += (size_t)MROWS * DI;
    float* yb     = ws; ws += (size_t)MROWS * DI;

    day_proj<<<dim3(BATCH * TSEQ), 256, 0, stream>>>(nI, dw, db, dayI, t_full);
    window_k<<<dim3(BATCH * LOUT), 256, 0, stream>>>(t_full, res);

    for (int i = 0; i < 2; ++i) {
        ln_kernel<<<dim3(MROWS), 256, 0, stream>>>(res, nw + (size_t)i * DM, nb + (size_t)i * DM, hn);
        // xz = hn @ ipw^T   (N=14336, K=3584)
        gemm128<0><<<dim3(112, 2, 1), 256, 0, stream>>>(
            hn, DM, ipw + (size_t)i * 2 * DI * DM, DM, xz, 2 * DI, DM, nullptr, 0);
        conv_silu<<<dim3(BATCH * LOUT), 256, 0, stream>>>(
            xz, cw + (size_t)i * DI * 4, cb + (size_t)i * DI, xq);
        // xdbl = xq @ xpw^T (N=256, K=7168) split-K=28 into partials
        gemm128<3><<<dim3(2, 2, 28), 256, 0, stream>>>(
            xq, DI, xpw + (size_t)i * 256 * DI, DI, xpart, 256, 256, nullptr, (long)MROWS * 256);
        reduce_part<<<dim3(256), 256, 0, stream>>>(xpart, xdbl);
        // delta = softplus(xdbl[:, :224] @ dtw^T + dtb)  (N=7168, K=224)
        gemm128<1><<<dim3(56, 2, 1), 256, 0, stream>>>(
            xdbl, 256, dtw + (size_t)i * DI * DTR, DTR, delta, DI, DTR,
            dtb + (size_t)i * DI, 0);
        scan_kernel<<<dim3(DI / 256, BATCH), 256, 0, stream>>>(
            delta, xq, xdbl, xz, Alog + (size_t)i * DI * DSTATE, Dp + (size_t)i * DI, yb);
        // res += yb @ opw^T  (N=3584, K=7168) split-K=4 with atomics (fused residual add)
        gemm128<2><<<dim3(28, 2, 4), 256, 0, stream>>>(
            yb, DI, opw + (size_t)i * DM * DI, DI, res, DM, DI / 4, nullptr, 0);
    }

    ln_fc<<<dim3(BATCH * LOUT), 256, 0, stream>>>(res, nfw, nfb, fcw, fcb, out);
}

// Round 2
// 1736.678 us; speedup vs baseline: 1.6658x; 1.6658x over previous
//
#include <hip/hip_runtime.h>
#include <hip/hip_bf16.h>
#include <math.h>

// ---- problem constants ----
#define BATCH   2
#define TSEQ    512
#define NDIM    256
#define STRIDE_ 4
#define KLEN    14
#define DM      3584        // NDIM*KLEN
#define DI      7168        // 2*DM
#define DTR     224
#define DSTATE  16
#define NCLS    41
#define LOUT    125
#define LPAD    128         // padded rows per batch
#define MROWS   256         // BATCH*LPAD

typedef __attribute__((ext_vector_type(8))) short bf8_t;   // 8 bf16
typedef __attribute__((ext_vector_type(4))) float f4_t;    // 4 fp32 acc

// fp32 -> bf16 RNE, two at a time
__device__ inline unsigned bfpair(float a, float b) {
    unsigned ua = __builtin_bit_cast(unsigned, a);
    unsigned ub = __builtin_bit_cast(unsigned, b);
    ua = (ua + 0x7fffu + ((ua >> 16) & 1u)) >> 16;
    ub = (ub + 0x7fffu + ((ub >> 16) & 1u)) >> 16;
    return ua | (ub << 16);
}
__device__ inline uint4 pack8(float4 a, float4 b) {
    return make_uint4(bfpair(a.x, a.y), bfpair(a.z, a.w),
                      bfpair(b.x, b.y), bfpair(b.z, b.w));
}

// ---------------------------------------------------------------------------
// day projection + softsign
__global__ void day_proj(const float* __restrict__ nI, const float* __restrict__ dw,
                         const float* __restrict__ db, const int* __restrict__ dayIdx,
                         float* __restrict__ t_full) {
    int bi = blockIdx.x;               // b*512 + i
    int b = bi >> 9;
    int di = dayIdx[b];
    int tid = threadIdx.x;             // k
    __shared__ float a_sh[256];
    a_sh[tid] = nI[(size_t)bi * 256 + tid];
    __syncthreads();
    const float* w = dw + (size_t)di * 65536;
    float acc = db[(size_t)di * 256 + tid];
    #pragma unroll 4
    for (int d = 0; d < 256; ++d) acc = fmaf(a_sh[d], w[d * 256 + tid], acc);
    t_full[(size_t)bi * 256 + tid] = acc / (1.f + fabsf(acc));
}

// window gather + zero the pad rows (l >= 125)
__global__ void window_k(const float* __restrict__ t_full, float* __restrict__ res) {
    int bl = blockIdx.x;               // 0..255
    int b = bl >> 7, l = bl & 127;
    size_t m = (size_t)b * LPAD + l;
    if (l >= LOUT) {
        for (int c = threadIdx.x; c < DM; c += 256) res[m * DM + c] = 0.f;
        return;
    }
    for (int c = threadIdx.x; c < DM; c += 256) {
        int d = c / KLEN, j = c - d * KLEN;
        res[m * DM + c] = t_full[((size_t)b * TSEQ + l * STRIDE_ + j) * 256 + d];
    }
}

// layernorm over DM -> packed bf16 A in fragment-major [G=k/8][m][8]
__global__ void ln_pack(const float* __restrict__ res, const float* __restrict__ w,
                        const float* __restrict__ b, short* __restrict__ hnp) {
    int m = blockIdx.x, tid = threadIdx.x;
    const float* row = res + (size_t)m * DM;
    float s = 0.f, ss = 0.f;
    for (int c = tid; c < DM; c += 256) { float v = row[c]; s += v; ss += v * v; }
    #pragma unroll
    for (int o = 32; o; o >>= 1) { s += __shfl_xor(s, o); ss += __shfl_xor(ss, o); }
    __shared__ float sm[8];
    int wid = tid >> 6;
    if ((tid & 63) == 0) { sm[wid] = s; sm[4 + wid] = ss; }
    __syncthreads();
    s = sm[0] + sm[1] + sm[2] + sm[3];
    ss = sm[4] + sm[5] + sm[6] + sm[7];
    float mu = s * (1.f / DM);
    float var = ss * (1.f / DM) - mu * mu;
    float rs = rsqrtf(var + 1e-5f);
    for (int G = tid; G < DM / 8; G += 256) {
        float4 f0 = *(const float4*)(row + G * 8);
        float4 f1 = *(const float4*)(row + G * 8 + 4);
        float4 w0 = *(const float4*)(w + G * 8);
        float4 w1 = *(const float4*)(w + G * 8 + 4);
        float4 b0 = *(const float4*)(b + G * 8);
        float4 b1 = *(const float4*)(b + G * 8 + 4);
        f0.x = (f0.x - mu) * rs * w0.x + b0.x; f0.y = (f0.y - mu) * rs * w0.y + b0.y;
        f0.z = (f0.z - mu) * rs * w0.z + b0.z; f0.w = (f0.w - mu) * rs * w0.w + b0.w;
        f1.x = (f1.x - mu) * rs * w1.x + b1.x; f1.y = (f1.y - mu) * rs * w1.y + b1.y;
        f1.z = (f1.z - mu) * rs * w1.z + b1.z; f1.w = (f1.w - mu) * rs * w1.w + b1.w;
        *(uint4*)&hnp[((size_t)G * 256 + m) * 8] = pack8(f0, f1);
    }
}

// generic fp32 row-major -> packed bf16 [G][m][8]; one block per row m
__global__ void pack_rows(const float* __restrict__ src, int lda, int nG,
                          short* __restrict__ dst) {
    int m = blockIdx.x;
    const float* row = src + (size_t)m * lda;
    for (int G = threadIdx.x; G < nG; G += 256) {
        float4 f0 = *(const float4*)(row + G * 8);
        float4 f1 = *(const float4*)(row + G * 8 + 4);
        *(uint4*)&dst[((size_t)G * 256 + m) * 8] = pack8(f0, f1);
    }
}

__global__ void zero_k(float* __restrict__ p) {
    size_t i = (size_t)(blockIdx.x * 256 + threadIdx.x) * 4;
    *(float4*)(p + i) = make_float4(0.f, 0.f, 0.f, 0.f);
}

// ---------------------------------------------------------------------------
// MFMA GEMM: C[256 x N] (+)= A[256 x K] * W[N x K]^T
// A pre-packed bf16 fragment-major [G=k/8][m][8]; W fp32, converted inline.
// Block tile 256x64, BK=32, 4 waves. EPI: 0=store, 1=softplus(bias+acc), 2=atomicAdd
template <int EPI>
__global__ __launch_bounds__(256)
void gemm_mfma(const short* __restrict__ Ap, const float* __restrict__ W, int ldw,
               float* __restrict__ C, int ldc, int kSteps,
               const float* __restrict__ bias) {
    __shared__ __align__(16) short a_sh[4][2056];   // 4 k-groups x 256 rows x 8 (+pad)
    __shared__ __align__(16) short w_sh[4][520];    // 4 k-groups x 64 cols x 8 (+pad)
    const int tid = threadIdx.x;
    const int wz = tid >> 6, lane = tid & 63;
    const int g = lane >> 4, i16 = lane & 15;
    const int n0 = blockIdx.x * 64;
    const int sBeg = blockIdx.z * kSteps;

    f4_t acc[4][4];
    #pragma unroll
    for (int r = 0; r < 4; ++r)
        #pragma unroll
        for (int c = 0; c < 4; ++c) acc[r][c] = (f4_t){0.f, 0.f, 0.f, 0.f};

    const float* wrow = W + (size_t)(n0 + lane) * ldw + wz * 8;
    const short* arow = Ap + (size_t)tid * 8;

    for (int s = sBeg; s < sBeg + kSteps; ++s) {
        // W fp32 -> regs (issued early, overlaps prior mfma)
        float4 wv0 = *(const float4*)(wrow + (size_t)s * 32);
        float4 wv1 = *(const float4*)(wrow + (size_t)s * 32 + 4);
        __syncthreads();                       // LDS free from previous step
        // A: async DMA global->LDS, 16B per lane, lane-ordered contiguous
        #pragma unroll
        for (int it = 0; it < 4; ++it) {
            const short* gp = arow + (size_t)(s * 4 + it) * 2048;
            __builtin_amdgcn_global_load_lds(
                (const __attribute__((address_space(1))) unsigned int*)gp,
                (__attribute__((address_space(3))) unsigned int*)&a_sh[it][tid * 8],
                16, 0, 0);
        }
        *(uint4*)&w_sh[wz][lane * 8] = pack8(wv0, wv1);
        __syncthreads();                       // drains vmcnt (DMA) + lds writes
        bf8_t af[4], wf[4];
        #pragma unroll
        for (int r = 0; r < 4; ++r)
            af[r] = *(const bf8_t*)&a_sh[g][(wz * 64 + r * 16 + i16) * 8];
        #pragma unroll
        for (int c = 0; c < 4; ++c)
            wf[c] = *(const bf8_t*)&w_sh[g][(c * 16 + i16) * 8];
        #pragma unroll
        for (int r = 0; r < 4; ++r)
            #pragma unroll
            for (int c = 0; c < 4; ++c)
                acc[r][c] = __builtin_amdgcn_mfma_f32_16x16x32_bf16(af[r], wf[c], acc[r][c], 0, 0, 0);
    }

    float bv[4];
    if (EPI == 1) {
        #pragma unroll
        for (int c = 0; c < 4; ++c) bv[c] = bias[n0 + c * 16 + i16];
    }
    #pragma unroll
    for (int r = 0; r < 4; ++r) {
        #pragma unroll
        for (int c = 0; c < 4; ++c) {
            int n = n0 + c * 16 + i16;
            #pragma unroll
            for (int v = 0; v < 4; ++v) {
                int m = wz * 64 + r * 16 + g * 4 + v;
                float val = acc[r][c][v];
                if (EPI == 0) {
                    C[(size_t)m * ldc + n] = val;
                } else if (EPI == 1) {
                    val += bv[c];
                    C[(size_t)m * ldc + n] = (val > 20.f) ? val : log1pf(expf(val));
                } else {
                    atomicAdd(&C[(size_t)m * ldc + n], val);
                }
            }
        }
    }
}

// causal depthwise conv (DCONV=4) + silu; writes fp32 xq AND packed bf16 xqp
__global__ void conv_silu_pack(const float* __restrict__ xz, const float* __restrict__ cw,
                               const float* __restrict__ cb, float* __restrict__ xq,
                               short* __restrict__ xqp) {
    int bl = blockIdx.x;
    int b = bl / 125, l = bl % 125;
    size_t m = (size_t)b * LPAD + l;
    for (int c0 = threadIdx.x * 8; c0 < DI; c0 += 2048) {
        float v[8];
        float4 cb0 = *(const float4*)(cb + c0);
        float4 cb1 = *(const float4*)(cb + c0 + 4);
        v[0] = cb0.x; v[1] = cb0.y; v[2] = cb0.z; v[3] = cb0.w;
        v[4] = cb1.x; v[5] = cb1.y; v[6] = cb1.z; v[7] = cb1.w;
        #pragma unroll
        for (int j = 0; j < 4; ++j) {
            int lj = l - 3 + j;
            if (lj < 0) continue;
            const float* xr = xz + ((size_t)b * LPAD + lj) * (2 * DI) + c0;
            float4 x0 = *(const float4*)xr;
            float4 x1 = *(const float4*)(xr + 4);
            float xa[8] = {x0.x, x0.y, x0.z, x0.w, x1.x, x1.y, x1.z, x1.w};
            #pragma unroll
            for (int k = 0; k < 8; ++k)
                v[k] = fmaf(xa[k], cw[(c0 + k) * 4 + j], v[k]);
        }
        float4 o0, o1;
        float* op = &o0.x;
        #pragma unroll
        for (int k = 0; k < 8; ++k) {
            float sv = v[k] / (1.f + expf(-v[k]));
            if (k < 4) (&o0.x)[k] = sv; else (&o1.x)[k - 4] = sv;
        }
        (void)op;
        *(float4*)(xq + m * DI + c0) = o0;
        *(float4*)(xq + m * DI + c0 + 4) = o1;
        *(uint4*)&xqp[(((size_t)c0 / 8) * 256 + m) * 8] = pack8(o0, o1);
    }
}

// selective scan: one thread per (b, channel c)
__global__ void scan_kernel(const float* __restrict__ delta, const float* __restrict__ xq,
                            const float* __restrict__ xdbl, const float* __restrict__ xz,
                            const float* __restrict__ Alog, const float* __restrict__ Dp,
                            float* __restrict__ y) {
    int c = blockIdx.x * 256 + threadIdx.x;   // 0..7167
    int b = blockIdx.y;
    float As[DSTATE], st[DSTATE];
    #pragma unroll
    for (int s = 0; s < DSTATE; ++s) {
        As[s] = -expf(Alog[(size_t)c * DSTATE + s]);
        st[s] = 0.f;
    }
    float dp = Dp[c];
    for (int l = 0; l < LOUT; ++l) {
        size_t m = (size_t)b * LPAD + l;
        float d  = delta[m * DI + c];
        float xv = xq[m * DI + c];
        float du = d * xv;
        const float* bc = xdbl + m * 256 + DTR;
        const float* cc = xdbl + m * 256 + DTR + DSTATE;
        float yv = 0.f;
        #pragma unroll
        for (int s = 0; s < DSTATE; ++s) {
            st[s] = fmaf(expf(d * As[s]), st[s], du * bc[s]);
            yv = fmaf(st[s], cc[s], yv);
        }
        float zv = xz[m * (2 * DI) + DI + c];
        y[m * DI + c] = (yv + xv * dp) * (zv / (1.f + expf(-zv)));
    }
}

// final layernorm + fc head
__global__ void ln_fc(const float* __restrict__ res, const float* __restrict__ wf,
                      const float* __restrict__ bf, const float* __restrict__ fcw,
                      const float* __restrict__ fcb, float* __restrict__ out) {
    __shared__ __align__(16) float hs[DM];
    __shared__ float sm[8];
    int bl = blockIdx.x;
    int b = bl / 125, l = bl % 125;
    size_t m = (size_t)b * LPAD + l;
    int tid = threadIdx.x;
    const float* row = res + m * DM;
    float s = 0.f, ss = 0.f;
    for (int c = tid; c < DM; c += 256) { float v = row[c]; s += v; ss += v * v; }
    #pragma unroll
    for (int o = 32; o; o >>= 1) { s += __shfl_xor(s, o); ss += __shfl_xor(ss, o); }
    int wid = tid >> 6;
    if ((tid & 63) == 0) { sm[wid] = s; sm[4 + wid] = ss; }
    __syncthreads();
    s = sm[0] + sm[1] + sm[2] + sm[3];
    ss = sm[4] + sm[5] + sm[6] + sm[7];
    float mu = s * (1.f / DM);
    float var = ss * (1.f / DM) - mu * mu;
    float rs = rsqrtf(var + 1e-5f);
    for (int c = tid; c < DM; c += 256) hs[c] = (row[c] - mu) * rs * wf[c] + bf[c];
    __syncthreads();
    int lane = tid & 63;
    for (int n = wid; n < NCLS; n += 4) {
        float acc = 0.f;
        for (int k = lane; k < DM; k += 64) acc = fmaf(hs[k], fcw[(size_t)n * DM + k], acc);
        #pragma unroll
        for (int o = 32; o; o >>= 1) acc += __shfl_xor(acc, o);
        if (lane == 0) out[((size_t)b * LOUT + l) * NCLS + n] = acc + fcb[n];
    }
}

// ---------------------------------------------------------------------------
extern "C" void kernel_launch(void* const* d_in, const int* in_sizes, int n_in,
                              void* d_out, int out_size, void* d_ws, size_t ws_size,
                              hipStream_t stream) {
    (void)in_sizes; (void)n_in; (void)out_size; (void)ws_size;
    const float* nI   = (const float*)d_in[0];
    const float* dw   = (const float*)d_in[1];
    const float* db   = (const float*)d_in[2];
    const float* nw   = (const float*)d_in[3];
    const float* nb   = (const float*)d_in[4];
    const float* ipw  = (const float*)d_in[5];
    const float* cw   = (const float*)d_in[6];
    const float* cb   = (const float*)d_in[7];
    const float* xpw  = (const float*)d_in[8];
    const float* dtw  = (const float*)d_in[9];
    const float* dtb  = (const float*)d_in[10];
    const float* Alog = (const float*)d_in[11];
    const float* Dp   = (const float*)d_in[12];
    const float* opw  = (const float*)d_in[13];
    const float* nfw  = (const float*)d_in[14];
    const float* nfb  = (const float*)d_in[15];
    const float* fcw  = (const float*)d_in[16];
    const float* fcb  = (const float*)d_in[17];
    const int*   dayI = (const int*)d_in[18];
    float* out = (float*)d_out;

    float* wsf = (float*)d_ws;
    float* t_full = wsf; wsf += 262144;                 // B*T*ND
    float* res    = wsf; wsf += (size_t)MROWS * DM;
    float* xz     = wsf; wsf += (size_t)MROWS * 2 * DI;
    float* xq     = wsf; wsf += (size_t)MROWS * DI;
    float* xdbl   = wsf; wsf += (size_t)MROWS * 256;
    float* delta  = wsf; wsf += (size_t)MROWS * DI;
    float* yb     = wsf; wsf += (size_t)MROWS * DI;
    short* wss = (short*)wsf;
    short* hnp   = wss; wss += (size_t)MROWS * DM;      // packed bf16
    short* xqp   = wss; wss += (size_t)MROWS * DI;
    short* xdblp = wss; wss += (size_t)MROWS * DTR;
    short* ybp   = wss; wss += (size_t)MROWS * DI;

    day_proj<<<dim3(BATCH * TSEQ), 256, 0, stream>>>(nI, dw, db, dayI, t_full);
    window_k<<<dim3(MROWS), 256, 0, stream>>>(t_full, res);

    for (int i = 0; i < 2; ++i) {
        ln_pack<<<dim3(MROWS), 256, 0, stream>>>(res, nw + (size_t)i * DM, nb + (size_t)i * DM, hnp);
        // xz = hn @ ipw^T   (N=14336, K=3584): 224 blocks, 112 k-steps
        gemm_mfma<0><<<dim3(224, 1, 1), 256, 0, stream>>>(
            hnp, ipw + (size_t)i * 2 * DI * DM, DM, xz, 2 * DI, 112, nullptr);
        conv_silu_pack<<<dim3(BATCH * LOUT), 256, 0, stream>>>(
            xz, cw + (size_t)i * DI * 4, cb + (size_t)i * DI, xq, xqp);
        zero_k<<<dim3(64), 256, 0, stream>>>(xdbl);
        // xdbl += xq @ xpw^T (N=256, K=7168): splitK=28
        gemm_mfma<2><<<dim3(4, 1, 28), 256, 0, stream>>>(
            xqp, xpw + (size_t)i * 256 * DI, DI, xdbl, 256, 8, nullptr);
        pack_rows<<<dim3(MROWS), 256, 0, stream>>>(xdbl, 256, DTR / 8, xdblp);
        // delta = softplus(xdbl[:, :224] @ dtw^T + dtb)  (N=7168, K=224)
        gemm_mfma<1><<<dim3(112, 1, 1), 256, 0, stream>>>(
            xdblp, dtw + (size_t)i * DI * DTR, DTR, delta, DI, 7, dtb + (size_t)i * DI);
        scan_kernel<<<dim3(DI / 256, BATCH), 256, 0, stream>>>(
            delta, xq, xdbl, xz, Alog + (size_t)i * DI * DSTATE, Dp + (size_t)i * DI, yb);
        pack_rows<<<dim3(MROWS), 256, 0, stream>>>(yb, DI, DI / 8, ybp);
        // res += yb @ opw^T  (N=3584, K=7168): splitK=4, fused residual add
        gemm_mfma<2><<<dim3(56, 1, 4), 256, 0, stream>>>(
            ybp, opw + (size_t)i * DM * DI, DI, res, DM, 56, nullptr);
    }

    ln_fc<<<dim3(BATCH * LOUT), 256, 0, stream>>>(res, nfw, nfb, fcw, fcb, out);
}

// Round 3
// 1355.201 us; speedup vs baseline: 2.1347x; 1.2815x over previous
//
#include <hip/hip_runtime.h>
#include <hip/hip_bf16.h>
#include <math.h>

// ---- problem constants ----
#define BATCH   2
#define TSEQ    512
#define NDIM    256
#define STRIDE_ 4
#define KLEN    14
#define DM      3584        // NDIM*KLEN
#define DI      7168        // 2*DM
#define DTR     224
#define DSTATE  16
#define NCLS    41
#define LOUT    125
#define LPAD    128         // padded rows per batch
#define MROWS   256         // BATCH*LPAD

typedef __attribute__((ext_vector_type(8))) short bf8_t;   // 8 bf16
typedef __attribute__((ext_vector_type(4))) float f4_t;    // 4 fp32 acc

// fp32 -> bf16 RNE, two at a time
__device__ inline unsigned bfpair(float a, float b) {
    unsigned ua = __builtin_bit_cast(unsigned, a);
    unsigned ub = __builtin_bit_cast(unsigned, b);
    ua = (ua + 0x7fffu + ((ua >> 16) & 1u)) >> 16;
    ub = (ub + 0x7fffu + ((ub >> 16) & 1u)) >> 16;
    return ua | (ub << 16);
}
__device__ inline uint4 pack8(float4 a, float4 b) {
    return make_uint4(bfpair(a.x, a.y), bfpair(a.z, a.w),
                      bfpair(b.x, b.y), bfpair(b.z, b.w));
}

// ---------------------------------------------------------------------------
// day projection + softsign
__global__ void day_proj(const float* __restrict__ nI, const float* __restrict__ dw,
                         const float* __restrict__ db, const int* __restrict__ dayIdx,
                         float* __restrict__ t_full) {
    int bi = blockIdx.x;               // b*512 + i
    int b = bi >> 9;
    int di = dayIdx[b];
    int tid = threadIdx.x;             // k
    __shared__ float a_sh[256];
    a_sh[tid] = nI[(size_t)bi * 256 + tid];
    __syncthreads();
    const float* w = dw + (size_t)di * 65536;
    float acc = db[(size_t)di * 256 + tid];
    #pragma unroll 8
    for (int d = 0; d < 256; ++d) acc = fmaf(a_sh[d], w[d * 256 + tid], acc);
    t_full[(size_t)bi * 256 + tid] = acc / (1.f + fabsf(acc));
}

// window gather + zero the pad rows (l >= 125)
__global__ void window_k(const float* __restrict__ t_full, float* __restrict__ res) {
    int bl = blockIdx.x;               // 0..255
    int b = bl >> 7, l = bl & 127;
    size_t m = (size_t)b * LPAD + l;
    if (l >= LOUT) {
        for (int c = threadIdx.x; c < DM; c += 256) res[m * DM + c] = 0.f;
        return;
    }
    for (int c = threadIdx.x; c < DM; c += 256) {
        int d = c / KLEN, j = c - d * KLEN;
        res[m * DM + c] = t_full[((size_t)b * TSEQ + l * STRIDE_ + j) * 256 + d];
    }
}

// layernorm over DM -> packed bf16 A in fragment-major [G=k/8][m][8]
__global__ void ln_pack(const float* __restrict__ res, const float* __restrict__ w,
                        const float* __restrict__ b, short* __restrict__ hnp) {
    int m = blockIdx.x, tid = threadIdx.x;
    const float* row = res + (size_t)m * DM;
    float s = 0.f, ss = 0.f;
    for (int c = tid; c < DM; c += 256) { float v = row[c]; s += v; ss += v * v; }
    #pragma unroll
    for (int o = 32; o; o >>= 1) { s += __shfl_xor(s, o); ss += __shfl_xor(ss, o); }
    __shared__ float sm[8];
    int wid = tid >> 6;
    if ((tid & 63) == 0) { sm[wid] = s; sm[4 + wid] = ss; }
    __syncthreads();
    s = sm[0] + sm[1] + sm[2] + sm[3];
    ss = sm[4] + sm[5] + sm[6] + sm[7];
    float mu = s * (1.f / DM);
    float var = ss * (1.f / DM) - mu * mu;
    float rs = rsqrtf(var + 1e-5f);
    for (int G = tid; G < DM / 8; G += 256) {
        float4 f0 = *(const float4*)(row + G * 8);
        float4 f1 = *(const float4*)(row + G * 8 + 4);
        float4 w0 = *(const float4*)(w + G * 8);
        float4 w1 = *(const float4*)(w + G * 8 + 4);
        float4 b0 = *(const float4*)(b + G * 8);
        float4 b1 = *(const float4*)(b + G * 8 + 4);
        f0.x = (f0.x - mu) * rs * w0.x + b0.x; f0.y = (f0.y - mu) * rs * w0.y + b0.y;
        f0.z = (f0.z - mu) * rs * w0.z + b0.z; f0.w = (f0.w - mu) * rs * w0.w + b0.w;
        f1.x = (f1.x - mu) * rs * w1.x + b1.x; f1.y = (f1.y - mu) * rs * w1.y + b1.y;
        f1.z = (f1.z - mu) * rs * w1.z + b1.z; f1.w = (f1.w - mu) * rs * w1.w + b1.w;
        *(uint4*)&hnp[((size_t)G * 256 + m) * 8] = pack8(f0, f1);
    }
}

// generic fp32 row-major -> packed bf16 [G][m][8]; one block per row m
__global__ void pack_rows(const float* __restrict__ src, int lda, int nG,
                          short* __restrict__ dst) {
    int m = blockIdx.x;
    const float* row = src + (size_t)m * lda;
    for (int G = threadIdx.x; G < nG; G += 256) {
        float4 f0 = *(const float4*)(row + G * 8);
        float4 f1 = *(const float4*)(row + G * 8 + 4);
        *(uint4*)&dst[((size_t)G * 256 + m) * 8] = pack8(f0, f1);
    }
}

__global__ void zero_k(float* __restrict__ p) {
    size_t i = (size_t)(blockIdx.x * 256 + threadIdx.x) * 4;
    *(float4*)(p + i) = make_float4(0.f, 0.f, 0.f, 0.f);
}

// ---------------------------------------------------------------------------
// MFMA GEMM, double-buffered: C[256 x N] (+)= A[256 x K] * W[N x K]^T
// A pre-packed bf16 fragment-major [G=k/8][m][8], staged via global_load_lds DMA.
// W fp32, cooperatively loaded (coalesced 128B row segments), packed to bf16 LDS.
// Block tile 256x64, BK=32, 4 waves. EPI: 0=store, 1=softplus(bias+acc), 2=atomicAdd
template <int EPI>
__global__ __launch_bounds__(256)
void gemm_mfma(const short* __restrict__ Ap, const float* __restrict__ W, int ldw,
               float* __restrict__ C, int ldc, int kSteps,
               const float* __restrict__ bias) {
    __shared__ __align__(16) short a_sh[2][4][2056];  // [buf][kgroup][m*8]
    __shared__ __align__(16) short w_sh[2][4][520];   // [buf][kgroup][n*8]
    const int tid = threadIdx.x;
    const int wz = tid >> 6, lane = tid & 63;
    const int g = lane >> 4, i16 = lane & 15;
    const int n0 = blockIdx.x * 64;
    const int sBeg = blockIdx.z * kSteps, sEnd = sBeg + kSteps;
    const int wr = tid >> 3;      // 0..31 (row within tile, +32 for second half)
    const int wq = tid & 7;       // quad-of-4-floats within 32-k

    f4_t acc[4][4];
    #pragma unroll
    for (int r = 0; r < 4; ++r)
        #pragma unroll
        for (int c = 0; c < 4; ++c) acc[r][c] = (f4_t){0.f, 0.f, 0.f, 0.f};

    const short* arow = Ap + (size_t)tid * 8;
    const float* wbase  = W + (size_t)(n0 + wr) * ldw + wq * 4;
    const float* wbase2 = wbase + (size_t)32 * ldw;

    // ---- prologue: fill buffer 0 for step sBeg ----
    float4 wv0 = *(const float4*)(wbase  + (size_t)sBeg * 32);
    float4 wv1 = *(const float4*)(wbase2 + (size_t)sBeg * 32);
    #pragma unroll
    for (int it = 0; it < 4; ++it)
        __builtin_amdgcn_global_load_lds(
            (const __attribute__((address_space(1))) unsigned int*)(arow + (size_t)(sBeg * 4 + it) * 2048),
            (__attribute__((address_space(3))) unsigned int*)&a_sh[0][it][tid * 8], 16, 0, 0);
    {
        uint2 p0 = {bfpair(wv0.x, wv0.y), bfpair(wv0.z, wv0.w)};
        *(uint2*)&w_sh[0][wq >> 1][wr * 8 + (wq & 1) * 4] = p0;
        uint2 p1 = {bfpair(wv1.x, wv1.y), bfpair(wv1.z, wv1.w)};
        *(uint2*)&w_sh[0][wq >> 1][(wr + 32) * 8 + (wq & 1) * 4] = p1;
    }
    int s1 = (sBeg + 1 < sEnd) ? sBeg + 1 : sEnd - 1;
    wv0 = *(const float4*)(wbase  + (size_t)s1 * 32);
    wv1 = *(const float4*)(wbase2 + (size_t)s1 * 32);

    for (int s = sBeg; s < sEnd; ++s) {
        const int cur = (s - sBeg) & 1, nxt = cur ^ 1;
        __syncthreads();   // a_sh[cur]/w_sh[cur] ready; [nxt] free (readers done pre-prev barrier)
        if (s + 1 < sEnd) {
            #pragma unroll
            for (int it = 0; it < 4; ++it)
                __builtin_amdgcn_global_load_lds(
                    (const __attribute__((address_space(1))) unsigned int*)(arow + (size_t)((s + 1) * 4 + it) * 2048),
                    (__attribute__((address_space(3))) unsigned int*)&a_sh[nxt][it][tid * 8], 16, 0, 0);
            uint2 p0 = {bfpair(wv0.x, wv0.y), bfpair(wv0.z, wv0.w)};
            *(uint2*)&w_sh[nxt][wq >> 1][wr * 8 + (wq & 1) * 4] = p0;
            uint2 p1 = {bfpair(wv1.x, wv1.y), bfpair(wv1.z, wv1.w)};
            *(uint2*)&w_sh[nxt][wq >> 1][(wr + 32) * 8 + (wq & 1) * 4] = p1;
            int s2 = (s + 2 < sEnd) ? s + 2 : sEnd - 1;
            wv0 = *(const float4*)(wbase  + (size_t)s2 * 32);
            wv1 = *(const float4*)(wbase2 + (size_t)s2 * 32);
        }
        bf8_t af[4], wf[4];
        #pragma unroll
        for (int r = 0; r < 4; ++r)
            af[r] = *(const bf8_t*)&a_sh[cur][g][(wz * 64 + r * 16 + i16) * 8];
        #pragma unroll
        for (int c = 0; c < 4; ++c)
            wf[c] = *(const bf8_t*)&w_sh[cur][g][(c * 16 + i16) * 8];
        #pragma unroll
        for (int r = 0; r < 4; ++r)
            #pragma unroll
            for (int c = 0; c < 4; ++c)
                acc[r][c] = __builtin_amdgcn_mfma_f32_16x16x32_bf16(af[r], wf[c], acc[r][c], 0, 0, 0);
    }

    float bv[4];
    if (EPI == 1) {
        #pragma unroll
        for (int c = 0; c < 4; ++c) bv[c] = bias[n0 + c * 16 + i16];
    }
    #pragma unroll
    for (int r = 0; r < 4; ++r) {
        #pragma unroll
        for (int c = 0; c < 4; ++c) {
            int n = n0 + c * 16 + i16;
            #pragma unroll
            for (int v = 0; v < 4; ++v) {
                int m = wz * 64 + r * 16 + g * 4 + v;
                float val = acc[r][c][v];
                if (EPI == 0) {
                    C[(size_t)m * ldc + n] = val;
                } else if (EPI == 1) {
                    val += bv[c];
                    C[(size_t)m * ldc + n] = (val > 20.f) ? val : log1pf(expf(val));
                } else {
                    atomicAdd(&C[(size_t)m * ldc + n], val);
                }
            }
        }
    }
}

// causal depthwise conv (DCONV=4) + silu; writes fp32 xq AND packed bf16 xqp
__global__ void conv_silu_pack(const float* __restrict__ xz, const float* __restrict__ cw,
                               const float* __restrict__ cb, float* __restrict__ xq,
                               short* __restrict__ xqp) {
    int bl = blockIdx.x;
    int b = bl / 125, l = bl % 125;
    size_t m = (size_t)b * LPAD + l;
    for (int c0 = threadIdx.x * 8; c0 < DI; c0 += 2048) {
        float v[8];
        float4 cb0 = *(const float4*)(cb + c0);
        float4 cb1 = *(const float4*)(cb + c0 + 4);
        v[0] = cb0.x; v[1] = cb0.y; v[2] = cb0.z; v[3] = cb0.w;
        v[4] = cb1.x; v[5] = cb1.y; v[6] = cb1.z; v[7] = cb1.w;
        #pragma unroll
        for (int j = 0; j < 4; ++j) {
            int lj = l - 3 + j;
            if (lj < 0) continue;
            const float* xr = xz + ((size_t)b * LPAD + lj) * (2 * DI) + c0;
            float4 x0 = *(const float4*)xr;
            float4 x1 = *(const float4*)(xr + 4);
            float xa[8] = {x0.x, x0.y, x0.z, x0.w, x1.x, x1.y, x1.z, x1.w};
            #pragma unroll
            for (int k = 0; k < 8; ++k)
                v[k] = fmaf(xa[k], cw[(c0 + k) * 4 + j], v[k]);
        }
        float4 o0, o1;
        #pragma unroll
        for (int k = 0; k < 8; ++k) {
            float sv = v[k] / (1.f + expf(-v[k]));
            if (k < 4) (&o0.x)[k] = sv; else (&o1.x)[k - 4] = sv;
        }
        *(float4*)(xq + m * DI + c0) = o0;
        *(float4*)(xq + m * DI + c0 + 4) = o1;
        *(uint4*)&xqp[(((size_t)c0 / 8) * 256 + m) * 8] = pack8(o0, o1);
    }
}

// selective scan, software-pipelined: one thread per (b, channel c)
union F16u { float4 v4[4]; float f[16]; };

__global__ void scan_kernel(const float* __restrict__ delta, const float* __restrict__ xq,
                            const float* __restrict__ xdbl, const float* __restrict__ xz,
                            const float* __restrict__ Alog, const float* __restrict__ Dp,
                            float* __restrict__ y) {
    int c = blockIdx.x * 256 + threadIdx.x;   // 0..7167
    int b = blockIdx.y;
    float As[DSTATE], st[DSTATE];
    #pragma unroll
    for (int s = 0; s < DSTATE; ++s) {
        As[s] = -expf(Alog[(size_t)c * DSTATE + s]);
        st[s] = 0.f;
    }
    float dp = Dp[c];
    size_t mb = (size_t)b * LPAD;
    // prefetch l=0
    float d_c = delta[mb * DI + c];
    float x_c = xq[mb * DI + c];
    float z_c = xz[mb * (2 * DI) + DI + c];
    F16u B_c, C_c;
    {
        const float4* p = (const float4*)(xdbl + mb * 256 + DTR);
        B_c.v4[0] = p[0]; B_c.v4[1] = p[1]; B_c.v4[2] = p[2]; B_c.v4[3] = p[3];
        C_c.v4[0] = p[4]; C_c.v4[1] = p[5]; C_c.v4[2] = p[6]; C_c.v4[3] = p[7];
    }
    for (int l = 0; l < LOUT; ++l) {
        float d_n = d_c, x_n = x_c, z_n = z_c;
        F16u B_n = B_c, C_n = C_c;
        if (l + 1 < LOUT) {
            size_t m = mb + l + 1;
            d_n = delta[m * DI + c];
            x_n = xq[m * DI + c];
            z_n = xz[m * (2 * DI) + DI + c];
            const float4* p = (const float4*)(xdbl + m * 256 + DTR);
            B_n.v4[0] = p[0]; B_n.v4[1] = p[1]; B_n.v4[2] = p[2]; B_n.v4[3] = p[3];
            C_n.v4[0] = p[4]; C_n.v4[1] = p[5]; C_n.v4[2] = p[6]; C_n.v4[3] = p[7];
        }
        float du = d_c * x_c;
        float yv = 0.f;
        #pragma unroll
        for (int s = 0; s < DSTATE; ++s) {
            st[s] = fmaf(expf(d_c * As[s]), st[s], du * B_c.f[s]);
            yv = fmaf(st[s], C_c.f[s], yv);
        }
        y[(mb + l) * DI + c] = (yv + x_c * dp) * (z_c / (1.f + expf(-z_c)));
        d_c = d_n; x_c = x_n; z_c = z_n; B_c = B_n; C_c = C_n;
    }
}

// final layernorm + fc head
__global__ void ln_fc(const float* __restrict__ res, const float* __restrict__ wf,
                      const float* __restrict__ bf, const float* __restrict__ fcw,
                      const float* __restrict__ fcb, float* __restrict__ out) {
    __shared__ __align__(16) float hs[DM];
    __shared__ float sm[8];
    int bl = blockIdx.x;
    int b = bl / 125, l = bl % 125;
    size_t m = (size_t)b * LPAD + l;
    int tid = threadIdx.x;
    const float* row = res + m * DM;
    float s = 0.f, ss = 0.f;
    for (int c = tid; c < DM; c += 256) { float v = row[c]; s += v; ss += v * v; }
    #pragma unroll
    for (int o = 32; o; o >>= 1) { s += __shfl_xor(s, o); ss += __shfl_xor(ss, o); }
    int wid = tid >> 6;
    if ((tid & 63) == 0) { sm[wid] = s; sm[4 + wid] = ss; }
    __syncthreads();
    s = sm[0] + sm[1] + sm[2] + sm[3];
    ss = sm[4] + sm[5] + sm[6] + sm[7];
    float mu = s * (1.f / DM);
    float var = ss * (1.f / DM) - mu * mu;
    float rs = rsqrtf(var + 1e-5f);
    for (int c = tid; c < DM; c += 256) hs[c] = (row[c] - mu) * rs * wf[c] + bf[c];
    __syncthreads();
    int lane = tid & 63;
    for (int n = wid; n < NCLS; n += 4) {
        const float* wrow = fcw + (size_t)n * DM;
        float a0 = 0.f, a1 = 0.f, a2 = 0.f, a3 = 0.f;
        for (int k = lane; k < DM; k += 256) {
            a0 = fmaf(hs[k],       wrow[k],       a0);
            a1 = fmaf(hs[k + 64],  wrow[k + 64],  a1);
            a2 = fmaf(hs[k + 128], wrow[k + 128], a2);
            a3 = fmaf(hs[k + 192], wrow[k + 192], a3);
        }
        float acc = (a0 + a1) + (a2 + a3);
        #pragma unroll
        for (int o = 32; o; o >>= 1) acc += __shfl_xor(acc, o);
        if (lane == 0) out[((size_t)b * LOUT + l) * NCLS + n] = acc + fcb[n];
    }
}

// ---------------------------------------------------------------------------
extern "C" void kernel_launch(void* const* d_in, const int* in_sizes, int n_in,
                              void* d_out, int out_size, void* d_ws, size_t ws_size,
                              hipStream_t stream) {
    (void)in_sizes; (void)n_in; (void)out_size; (void)ws_size;
    const float* nI   = (const float*)d_in[0];
    const float* dw   = (const float*)d_in[1];
    const float* db   = (const float*)d_in[2];
    const float* nw   = (const float*)d_in[3];
    const float* nb   = (const float*)d_in[4];
    const float* ipw  = (const float*)d_in[5];
    const float* cw   = (const float*)d_in[6];
    const float* cb   = (const float*)d_in[7];
    const float* xpw  = (const float*)d_in[8];
    const float* dtw  = (const float*)d_in[9];
    const float* dtb  = (const float*)d_in[10];
    const float* Alog = (const float*)d_in[11];
    const float* Dp   = (const float*)d_in[12];
    const float* opw  = (const float*)d_in[13];
    const float* nfw  = (const float*)d_in[14];
    const float* nfb  = (const float*)d_in[15];
    const float* fcw  = (const float*)d_in[16];
    const float* fcb  = (const float*)d_in[17];
    const int*   dayI = (const int*)d_in[18];
    float* out = (float*)d_out;

    float* wsf = (float*)d_ws;
    float* t_full = wsf; wsf += 262144;                 // B*T*ND
    float* res    = wsf; wsf += (size_t)MROWS * DM;
    float* xz     = wsf; wsf += (size_t)MROWS * 2 * DI;
    float* xq     = wsf; wsf += (size_t)MROWS * DI;
    float* xdbl   = wsf; wsf += (size_t)MROWS * 256;
    float* delta  = wsf; wsf += (size_t)MROWS * DI;
    float* yb     = wsf; wsf += (size_t)MROWS * DI;
    short* wss = (short*)wsf;
    short* hnp   = wss; wss += (size_t)MROWS * DM;      // packed bf16
    short* xqp   = wss; wss += (size_t)MROWS * DI;
    short* xdblp = wss; wss += (size_t)MROWS * DTR;
    short* ybp   = wss; wss += (size_t)MROWS * DI;

    day_proj<<<dim3(BATCH * TSEQ), 256, 0, stream>>>(nI, dw, db, dayI, t_full);
    window_k<<<dim3(MROWS), 256, 0, stream>>>(t_full, res);

    for (int i = 0; i < 2; ++i) {
        ln_pack<<<dim3(MROWS), 256, 0, stream>>>(res, nw + (size_t)i * DM, nb + (size_t)i * DM, hnp);
        // xz = hn @ ipw^T   (N=14336, K=3584): 224 blocks, 112 k-steps
        gemm_mfma<0><<<dim3(224, 1, 1), 256, 0, stream>>>(
            hnp, ipw + (size_t)i * 2 * DI * DM, DM, xz, 2 * DI, 112, nullptr);
        conv_silu_pack<<<dim3(BATCH * LOUT), 256, 0, stream>>>(
            xz, cw + (size_t)i * DI * 4, cb + (size_t)i * DI, xq, xqp);
        zero_k<<<dim3(64), 256, 0, stream>>>(xdbl);
        // xdbl += xq @ xpw^T (N=256, K=7168): splitK=28
        gemm_mfma<2><<<dim3(4, 1, 28), 256, 0, stream>>>(
            xqp, xpw + (size_t)i * 256 * DI, DI, xdbl, 256, 8, nullptr);
        pack_rows<<<dim3(MROWS), 256, 0, stream>>>(xdbl, 256, DTR / 8, xdblp);
        // delta = softplus(xdbl[:, :224] @ dtw^T + dtb)  (N=7168, K=224)
        gemm_mfma<1><<<dim3(112, 1, 1), 256, 0, stream>>>(
            xdblp, dtw + (size_t)i * DI * DTR, DTR, delta, DI, 7, dtb + (size_t)i * DI);
        scan_kernel<<<dim3(DI / 256, BATCH), 256, 0, stream>>>(
            delta, xq, xdbl, xz, Alog + (size_t)i * DI * DSTATE, Dp + (size_t)i * DI, yb);
        pack_rows<<<dim3(MROWS), 256, 0, stream>>>(yb, DI, DI / 8, ybp);
        // res += yb @ opw^T  (N=3584, K=7168): splitK=8, fused residual add
        gemm_mfma<2><<<dim3(56, 1, 8), 256, 0, stream>>>(
            ybp, opw + (size_t)i * DM * DI, DI, res, DM, 28, nullptr);
    }

    ln_fc<<<dim3(BATCH * LOUT), 256, 0, stream>>>(res, nfw, nfb, fcw, fcb, out);
}